// Round 1
// baseline (596.716 us; speedup 1.0000x reference)
//
#include <hip/hip_runtime.h>

// SoftmaxRBM fused single-kernel: prob = softmax_groups16( hidden @ W^T + a ).
// Shape-specialized for tall-skinny GEMM: M=NVIS=65536, N=POP=1024, K=NH=256.
//
// Structure (replaces 3-kernel m97-recipe pipeline):
//  - hidden panel [128 b-rows][K=256] converted fp32->bf16 into LDS ONCE per
//    block (64 KB), laid out as 8 K-slices of [128][32] so every MFMA B-frag
//    read is a contiguous 1 KB ds_read_b128 tile (conflict-minimal).
//  - W streamed global->reg as fp32 with in-register truncation to bf16
//    (same numerics as the previous pre-convert kernel). No LDS for W, no
//    global_load_lds, NO barriers in the K-loop -> no vmcnt(0) drains.
//  - Each wave owns a 64x128 output tile: acc[4][8] f32x4 (128 VGPR),
//    prefetches next K-frag of W under the 32-MFMA cluster.
//  - Fused segmented softmax (16 v-rows = one MFMA tile, quad-shfl reduce)
//    + non-temporal f32x4 stores (don't evict W from L2/L3).

typedef short  bf16x8 __attribute__((ext_vector_type(8)));
typedef float  f32x4  __attribute__((ext_vector_type(4)));

#define NH    256
#define POP   1024
#define NVIS  65536
#define BN    128     // batch cols per block (POP/BN = 8 panels)
#define MB    1024    // visible rows per block (NVIS/MB = 64 blocks)
#define SUBM  64      // visible rows per wave-subtile

__device__ __forceinline__ unsigned pack2bf(float lo, float hi) {
  return (__float_as_uint(hi) & 0xffff0000u) | (__float_as_uint(lo) >> 16);
}

__global__ __launch_bounds__(256, 2) void rbm_fused_kernel(
    const float* __restrict__ Hg,  // [POP][NH]   fp32
    const float* __restrict__ Wg,  // [NVIS][NH]  fp32
    const float* __restrict__ Ag,  // [NVIS]      fp32
    float* __restrict__ out)       // [POP][NVIS] fp32
{
  // B panel: 8 K-slices of [BN rows][32 k] bf16 = 64 KB.
  __shared__ short sB[8 * BN * 32];

  const int tid  = threadIdx.x;
  const int lane = tid & 63;
  const int wave = tid >> 6;
  const int quad = lane >> 4;
  const int col  = lane & 15;
  const int n_base = blockIdx.x * BN;
  const int m_blk  = blockIdx.y * MB;

  // ---- one-time: stage hidden panel fp32 -> bf16 into LDS [j][row][k32]
  {
    const int row  = tid >> 1;          // 0..127
    const int half = (tid & 1) * 16;    // 0 or 16
    const float* src = Hg + (size_t)(n_base + row) * NH + half;
    #pragma unroll
    for (int j = 0; j < 8; ++j) {
      const float4 f0 = ((const float4*)(src + j * 32))[0];
      const float4 f1 = ((const float4*)(src + j * 32))[1];
      const float4 f2 = ((const float4*)(src + j * 32))[2];
      const float4 f3 = ((const float4*)(src + j * 32))[3];
      uint4 u0, u1;
      u0.x = pack2bf(f0.x, f0.y); u0.y = pack2bf(f0.z, f0.w);
      u0.z = pack2bf(f1.x, f1.y); u0.w = pack2bf(f1.z, f1.w);
      u1.x = pack2bf(f2.x, f2.y); u1.y = pack2bf(f2.z, f2.w);
      u1.z = pack2bf(f3.x, f3.y); u1.w = pack2bf(f3.z, f3.w);
      *(uint4*)&sB[(j * BN + row) * 32 + half]     = u0;
      *(uint4*)&sB[(j * BN + row) * 32 + half + 8] = u1;
    }
  }
  __syncthreads();   // the ONLY barrier in the kernel

  // ---- per-wave subtiles: 4 subtiles of 64 rows, wave-contiguous 256 rows
  #pragma unroll 1
  for (int t = 0; t < MB / (4 * SUBM); ++t) {
    const int m0 = m_blk + wave * (MB / 4) + t * SUBM;

    f32x4 acc[4][8];
    #pragma unroll
    for (int mt = 0; mt < 4; ++mt)
      #pragma unroll
      for (int nt = 0; nt < 8; ++nt)
        acc[mt][nt] = f32x4{0.f, 0.f, 0.f, 0.f};

    // A-frag source rows: W[m0 + mt*16 + col][ j*32 + quad*8 .. +7 ] (fp32)
    const float* ap[4];
    #pragma unroll
    for (int mt = 0; mt < 4; ++mt)
      ap[mt] = Wg + (size_t)(m0 + mt * 16 + col) * NH + quad * 8;

    // prefetch j=0
    float4 pf[4][2];
    #pragma unroll
    for (int mt = 0; mt < 4; ++mt) {
      pf[mt][0] = ((const float4*)ap[mt])[0];
      pf[mt][1] = ((const float4*)ap[mt])[1];
    }

    #pragma unroll
    for (int j = 0; j < 8; ++j) {
      // pack current fp32 frags -> bf16 (truncation, same as cvt kernel)
      bf16x8 af[4];
      #pragma unroll
      for (int mt = 0; mt < 4; ++mt) {
        union { bf16x8 v; uint4 u; } cv;
        cv.u.x = pack2bf(pf[mt][0].x, pf[mt][0].y);
        cv.u.y = pack2bf(pf[mt][0].z, pf[mt][0].w);
        cv.u.z = pack2bf(pf[mt][1].x, pf[mt][1].y);
        cv.u.w = pack2bf(pf[mt][1].z, pf[mt][1].w);
        af[mt] = cv.v;
      }
      // issue next-j W loads (latency hidden under ds_read + 32 MFMA)
      if (j < 7) {
        #pragma unroll
        for (int mt = 0; mt < 4; ++mt) {
          const float4* p = (const float4*)(ap[mt] + (j + 1) * 32);
          pf[mt][0] = p[0];
          pf[mt][1] = p[1];
        }
      }
      // B frags from LDS (contiguous 1 KB per (j,nt) tile) + MFMA cluster
      const short* bbase = &sB[(j * BN) * 32 + quad * 8];
      #pragma unroll
      for (int nt = 0; nt < 8; ++nt) {
        const bf16x8 bf = *(const bf16x8*)(bbase + (nt * 16 + col) * 32);
        #pragma unroll
        for (int mt = 0; mt < 4; ++mt)
          acc[mt][nt] = __builtin_amdgcn_mfma_f32_16x16x32_bf16(
              af[mt], bf, acc[mt][nt], 0, 0, 0);
      }
    }

    // ---- epilogue: +a[v], softmax over the 16 v-rows of each MFMA tile.
    // C/D layout: col(n)=lane&15, row(m)=quad*4+reg -> lane holds 4 consec v.
    #pragma unroll
    for (int mt = 0; mt < 4; ++mt) {
      const int v0 = m0 + mt * 16 + quad * 4;
      const float4 av = *(const float4*)(Ag + v0);
      #pragma unroll
      for (int nt = 0; nt < 8; ++nt) {
        const int b = n_base + nt * 16 + col;
        f32x4 c = acc[mt][nt];
        float x0 = c[0] + av.x, x1 = c[1] + av.y;
        float x2 = c[2] + av.z, x3 = c[3] + av.w;
        float mx = fmaxf(fmaxf(x0, x1), fmaxf(x2, x3));
        mx = fmaxf(mx, __shfl_xor(mx, 16));
        mx = fmaxf(mx, __shfl_xor(mx, 32));
        float e0 = __expf(x0 - mx), e1 = __expf(x1 - mx);
        float e2 = __expf(x2 - mx), e3 = __expf(x3 - mx);
        float s = (e0 + e1) + (e2 + e3);
        s += __shfl_xor(s, 16);
        s += __shfl_xor(s, 32);
        const float inv = 1.0f / s;
        f32x4 o;
        o[0] = e0 * inv; o[1] = e1 * inv; o[2] = e2 * inv; o[3] = e3 * inv;
        // non-temporal: don't let 268 MB of streaming writes evict W.
        __builtin_nontemporal_store(o, (f32x4*)(out + (size_t)b * NVIS + v0));
      }
    }
  }
}

extern "C" void kernel_launch(void* const* d_in, const int* in_sizes, int n_in,
                              void* d_out, int out_size, void* d_ws, size_t ws_size,
                              hipStream_t stream) {
  const float* hidden = (const float*)d_in[0]; // [1024][256]
  const float* W      = (const float*)d_in[1]; // [65536][256]
  const float* a      = (const float*)d_in[2]; // [65536]
  float* out          = (float*)d_out;         // [1024][65536]
  (void)d_ws; (void)ws_size;

  dim3 grid(POP / BN, NVIS / MB);              // (8, 64) = 512 blocks
  rbm_fused_kernel<<<grid, 256, 0, stream>>>(hidden, W, a, out);
}

// Round 3
// 408.834 us; speedup vs baseline: 1.4596x; 1.4596x over previous
//
#include <hip/hip_runtime.h>

// SoftmaxRBM fused single-kernel: prob = softmax_groups16( hidden @ W^T + a ).
// M=NVIS=65536, N=POP=1024, K=NH=256.
//
// v2 (RESUBMIT — round-2 bench was an infra failure, kernel never measured).
// v2 vs v1: ONE 64x128 subtile per wave (no subtile loop). Rationale: vmcnt
// is shared by loads and stores and retires in issue order; v1's per-subtile
// epilogue stores forced every next-subtile W-load wait to drain 32 streaming
// HBM stores (the measured ~3900 cyc/j-step stall). Here stores are terminal:
//   - stage H panel [128][256] fp32->bf16 in LDS once (64 KB), 1 barrier
//   - barrier-free unrolled K-loop, W fp32 streamed global->reg with
//     in-register bf16 truncation, 1-deep prefetch
//   - epilogue split: phase A = bias loads + softmax math (writes back into
//     acc), phase B = 32 non-temporal stores, then the wave retires.
// Register budget deliberately matches v1 (128 arch VGPR + 128 acc AGPR =
// exactly 2 waves/SIMD at launch_bounds(256,2)) - do not add prefetch depth.

typedef short  bf16x8 __attribute__((ext_vector_type(8)));
typedef float  f32x4  __attribute__((ext_vector_type(4)));

#define NH    256
#define POP   1024
#define NVIS  65536
#define BN    128     // batch cols per block (POP/BN = 8 panels)
#define MBLK  256     // visible rows per block = 4 waves x 64

__device__ __forceinline__ unsigned pack2bf(float lo, float hi) {
  return (__float_as_uint(hi) & 0xffff0000u) | (__float_as_uint(lo) >> 16);
}

__global__ __launch_bounds__(256, 2) void rbm_fused_kernel(
    const float* __restrict__ Hg,  // [POP][NH]   fp32
    const float* __restrict__ Wg,  // [NVIS][NH]  fp32
    const float* __restrict__ Ag,  // [NVIS]      fp32
    float* __restrict__ out)       // [POP][NVIS] fp32
{
  // B panel: 8 K-slices of [BN rows][32 k] bf16 = 64 KB.
  __shared__ short sB[8 * BN * 32];

  const int tid  = threadIdx.x;
  const int lane = tid & 63;
  const int wave = tid >> 6;
  const int quad = lane >> 4;
  const int col  = lane & 15;
  const int n_base = blockIdx.x * BN;
  const int m0     = blockIdx.y * MBLK + wave * 64;   // this wave's 64 rows

  // ---- one-time: stage hidden panel fp32 -> bf16 into LDS [j][row][k32]
  {
    const int row  = tid >> 1;          // 0..127
    const int half = (tid & 1) * 16;    // 0 or 16
    const float* src = Hg + (size_t)(n_base + row) * NH + half;
    #pragma unroll
    for (int j = 0; j < 8; ++j) {
      const float4 f0 = ((const float4*)(src + j * 32))[0];
      const float4 f1 = ((const float4*)(src + j * 32))[1];
      const float4 f2 = ((const float4*)(src + j * 32))[2];
      const float4 f3 = ((const float4*)(src + j * 32))[3];
      uint4 u0, u1;
      u0.x = pack2bf(f0.x, f0.y); u0.y = pack2bf(f0.z, f0.w);
      u0.z = pack2bf(f1.x, f1.y); u0.w = pack2bf(f1.z, f1.w);
      u1.x = pack2bf(f2.x, f2.y); u1.y = pack2bf(f2.z, f2.w);
      u1.z = pack2bf(f3.x, f3.y); u1.w = pack2bf(f3.z, f3.w);
      *(uint4*)&sB[(j * BN + row) * 32 + half]     = u0;
      *(uint4*)&sB[(j * BN + row) * 32 + half + 8] = u1;
    }
  }
  __syncthreads();   // the ONLY barrier in the kernel

  f32x4 acc[4][8];
  #pragma unroll
  for (int mt = 0; mt < 4; ++mt)
    #pragma unroll
    for (int nt = 0; nt < 8; ++nt)
      acc[mt][nt] = f32x4{0.f, 0.f, 0.f, 0.f};

  // A-frag source rows: W[m0 + mt*16 + col][ j*32 + quad*8 .. +7 ] (fp32)
  const float* ap[4];
  #pragma unroll
  for (int mt = 0; mt < 4; ++mt)
    ap[mt] = Wg + (size_t)(m0 + mt * 16 + col) * NH + quad * 8;

  // prefetch j=0
  float4 pf[4][2];
  #pragma unroll
  for (int mt = 0; mt < 4; ++mt) {
    pf[mt][0] = ((const float4*)ap[mt])[0];
    pf[mt][1] = ((const float4*)ap[mt])[1];
  }

  #pragma unroll
  for (int j = 0; j < 8; ++j) {
    // pack current fp32 frags -> bf16 (truncation, same numerics as before)
    bf16x8 af[4];
    #pragma unroll
    for (int mt = 0; mt < 4; ++mt) {
      union { bf16x8 v; uint4 u; } cv;
      cv.u.x = pack2bf(pf[mt][0].x, pf[mt][0].y);
      cv.u.y = pack2bf(pf[mt][0].z, pf[mt][0].w);
      cv.u.z = pack2bf(pf[mt][1].x, pf[mt][1].y);
      cv.u.w = pack2bf(pf[mt][1].z, pf[mt][1].w);
      af[mt] = cv.v;
    }
    // issue next-j W loads (hidden under ds_read + 32 MFMA; no stores are
    // outstanding anywhere in this loop, so waits are precise vmcnt(N))
    if (j < 7) {
      #pragma unroll
      for (int mt = 0; mt < 4; ++mt) {
        const float4* p = (const float4*)(ap[mt] + (j + 1) * 32);
        pf[mt][0] = p[0];
        pf[mt][1] = p[1];
      }
    }
    // B frags from LDS + MFMA cluster
    const short* bbase = &sB[(j * BN) * 32 + quad * 8];
    #pragma unroll
    for (int nt = 0; nt < 8; ++nt) {
      const bf16x8 bf = *(const bf16x8*)(bbase + (nt * 16 + col) * 32);
      #pragma unroll
      for (int mt = 0; mt < 4; ++mt)
        acc[mt][nt] = __builtin_amdgcn_mfma_f32_16x16x32_bf16(
            af[mt], bf, acc[mt][nt], 0, 0, 0);
    }
  }

  // ---- epilogue phase A: bias + segmented softmax, written back into acc.
  // All loads (Ag) precede ALL stores -> no load ever waits behind a store.
  // C/D layout: col(n)=lane&15, row(m)=quad*4+reg -> lane holds 4 consec v.
  #pragma unroll
  for (int mt = 0; mt < 4; ++mt) {
    const int v0 = m0 + mt * 16 + quad * 4;
    const float4 av = *(const float4*)(Ag + v0);
    #pragma unroll
    for (int nt = 0; nt < 8; ++nt) {
      f32x4 c = acc[mt][nt];
      float x0 = c[0] + av.x, x1 = c[1] + av.y;
      float x2 = c[2] + av.z, x3 = c[3] + av.w;
      float mx = fmaxf(fmaxf(x0, x1), fmaxf(x2, x3));
      mx = fmaxf(mx, __shfl_xor(mx, 16));   // DS/permute path: lgkmcnt only
      mx = fmaxf(mx, __shfl_xor(mx, 32));
      float e0 = __expf(x0 - mx), e1 = __expf(x1 - mx);
      float e2 = __expf(x2 - mx), e3 = __expf(x3 - mx);
      float s = (e0 + e1) + (e2 + e3);
      s += __shfl_xor(s, 16);
      s += __shfl_xor(s, 32);
      const float inv = 1.0f / s;
      f32x4 o;
      o[0] = e0 * inv; o[1] = e1 * inv; o[2] = e2 * inv; o[3] = e3 * inv;
      acc[mt][nt] = o;
    }
  }

  // ---- epilogue phase B: terminal non-temporal stores; wave retires after.
  #pragma unroll
  for (int mt = 0; mt < 4; ++mt) {
    const int v0 = m0 + mt * 16 + quad * 4;
    #pragma unroll
    for (int nt = 0; nt < 8; ++nt) {
      const int b = n_base + nt * 16 + col;
      // non-temporal: don't let 268 MB of streaming writes evict W from L2/L3.
      __builtin_nontemporal_store(acc[mt][nt],
                                  (f32x4*)(out + (size_t)b * NVIS + v0));
    }
  }
}

extern "C" void kernel_launch(void* const* d_in, const int* in_sizes, int n_in,
                              void* d_out, int out_size, void* d_ws, size_t ws_size,
                              hipStream_t stream) {
  const float* hidden = (const float*)d_in[0]; // [1024][256]
  const float* W      = (const float*)d_in[1]; // [65536][256]
  const float* a      = (const float*)d_in[2]; // [65536]
  float* out          = (float*)d_out;         // [1024][65536]
  (void)d_ws; (void)ws_size;

  dim3 grid(POP / BN, NVIS / MBLK);            // (8, 256) = 2048 blocks
  rbm_fused_kernel<<<grid, 256, 0, stream>>>(hidden, W, a, out);
}